// Round 6
// baseline (1388.422 us; speedup 1.0000x reference)
//
#include <hip/hip_runtime.h>
#include <cstdint>

#define NTOK 8192
#define DMODEL 1024
#define HDDIM 4096
#define NVEC 32

typedef float f32x4_v __attribute__((ext_vector_type(4)));
typedef __bf16 bf16x8 __attribute__((ext_vector_type(8)));
typedef unsigned short u16x4 __attribute__((ext_vector_type(4)));

__device__ __forceinline__ unsigned short f2bf(float f) {
  union { float f; uint32_t u; } x; x.f = f;
  uint32_t r = (x.u + 0x7FFFu + ((x.u >> 16) & 1u)) >> 16;
  return (unsigned short)r;
}

// tanh-form GELU via single v_exp_f32; |err| vs erf-gelu <= ~5e-4.
__device__ __forceinline__ float gelu_fast(float x) {
  float t = x * x;
  float z = x * (2.3022082f + 0.1029440f * t);  // 2*sqrt(2/pi)*log2e*(1,0.044715)
  float e = exp2f(-z);
  return x / (1.0f + e);
}

#define VMCNT(n) asm volatile("s_waitcnt vmcnt(" #n ")" ::: "memory")

__device__ __forceinline__ void gload16(const unsigned short* g, unsigned short* lds)
{
  __builtin_amdgcn_global_load_lds((__attribute__((address_space(1))) void*)g,
                                   (__attribute__((address_space(3))) void*)lds,
                                   16, 0, 0);
}

// ---------------------------------------------------------------------------
// Reconstruct + transpose body: outT[y][x] (bf16, ld=X) = sum_v c[v]*basis[v][x][y]
// ---------------------------------------------------------------------------
__device__ __forceinline__
void reconstruct_body(const float* __restrict__ basis,
                      const float* __restrict__ coeffs,
                      int e, unsigned short* __restrict__ outT,
                      int X, int Y, int tile, char* smem)
{
  float (*lds)[65] = (float (*)[65])smem;
  const int xtiles = X >> 6;
  const int bx = tile % xtiles;
  const int by = tile / xtiles;
  const int x0 = bx << 6, y0 = by << 6;
  const int t  = threadIdx.x;
  const int y4 = t & 15;
  const int xg = t >> 4;

  f32x4_v acc[4];
  #pragma unroll
  for (int i = 0; i < 4; ++i) acc[i] = (f32x4_v){0.f, 0.f, 0.f, 0.f};

  const size_t mat = (size_t)X * (size_t)Y;
  const float* base = basis + (size_t)(x0 + xg * 4) * Y + (y0 + y4 * 4);

  #pragma unroll 2
  for (int v = 0; v < NVEC; ++v) {
    const float cv = coeffs[e * NVEC + v];
    const float* pv = base + (size_t)v * mat;
    #pragma unroll
    for (int i = 0; i < 4; ++i) {
      f32x4_v d = *(const f32x4_v*)(pv + (size_t)i * Y);
      acc[i] += cv * d;
    }
  }

  #pragma unroll
  for (int i = 0; i < 4; ++i)
    #pragma unroll
    for (int j = 0; j < 4; ++j)
      lds[xg * 4 + i][y4 * 4 + j] = acc[i][j];
  __syncthreads();

  const int x4 = t & 15;
  const int yr = t >> 4;
  #pragma unroll
  for (int yy = 0; yy < 4; ++yy) {
    const int y = yr + yy * 16;
    u16x4 u;
    #pragma unroll
    for (int i = 0; i < 4; ++i) u[i] = f2bf(lds[x4 * 4 + i][y]);
    *(u16x4*)(outT + (size_t)(y0 + y) * X + x0 + x4 * 4) = u;
  }
}

// ---------------------------------------------------------------------------
// Merged memory kernel: rec_up (0..1023) | rec_dn (1024..2047) | cvt (2048..2559)
// ---------------------------------------------------------------------------
#define CVT_BLKS 512

__global__ __launch_bounds__(256)
void mem_kernel(const float* __restrict__ inputs,
                const float* __restrict__ basis_up,
                const float* __restrict__ basis_down,
                const float* __restrict__ cup,
                const float* __restrict__ cdn,
                const int* __restrict__ eidx_p,
                unsigned short* __restrict__ A_bf,
                unsigned short* __restrict__ WupT,
                unsigned short* __restrict__ WdnT)
{
  __shared__ __align__(16) char smem[64 * 65 * 4];
  const int bid = blockIdx.x;
  if (bid < 1024) {
    reconstruct_body(basis_up, cup, *eidx_p, WupT, DMODEL, HDDIM, bid, smem);
  } else if (bid < 2048) {
    reconstruct_body(basis_down, cdn, *eidx_p, WdnT, HDDIM, DMODEL, bid - 1024, smem);
  } else {
    const int n4 = NTOK * DMODEL / 4;
    const int stride = CVT_BLKS * 256;
    for (int i = (bid - 2048) * 256 + threadIdx.x; i < n4; i += stride) {
      f32x4_v v = ((const f32x4_v*)inputs)[i];
      u16x4 u;
      #pragma unroll
      for (int j = 0; j < 4; ++j) u[j] = f2bf(v[j]);
      ((u16x4*)A_bf)[i] = u;
    }
  }
}

// ---------------------------------------------------------------------------
// 8-wave deep-pipelined GEMM (unchanged from R5)
// ---------------------------------------------------------------------------
template<int BM, int BN, int CHM, int CHN, int EPI>
__global__ __launch_bounds__(512)
void gemm8p(const unsigned short* __restrict__ A,
            const unsigned short* __restrict__ Bt,
            unsigned short* __restrict__ Cbf,
            float* __restrict__ Cf,
            const float* __restrict__ bias,
            const int* __restrict__ eidx_p,
            int M, int N, int K)
{
  constexpr int BK   = 32;
  constexpr int FM   = BM / 32;
  constexpr int FN   = BN / 64;
  constexpr int P    = (FM * FN) / 16;
  constexpr int SLOT = (BM + BN) * BK * 2;
  constexpr int L    = SLOT / 16 / 512;
  constexpr int LPP  = L / P;
  constexpr int ACH  = BM * 4;
  constexpr int JA   = ACH / 512;

  __shared__ __align__(16) char smem[4 * SLOT];

  const int nb  = N / BN;
  const int ncn = nb / CHN;
  const int xcd = blockIdx.x & 7;
  const int idx = blockIdx.x >> 3;
  const int bm  = (xcd / ncn) * CHM + idx / CHN;
  const int bn  = (xcd % ncn) * CHN + idx % CHN;
  const int m0 = bm * BM, n0 = bn * BN;

  const int tid = threadIdx.x;
  const int w = tid >> 6, l = tid & 63;
  const int wm = w >> 2, wn = w & 3;
  const int lrow = l & 15, lkc = l >> 4;

  uint32_t soff[L];
  #pragma unroll
  for (int j = 0; j < L; ++j) {
    const int q = tid + j * 512;
    if (j < JA) {
      const int r = q >> 2, cs = (q & 3) ^ ((r >> 1) & 3);
      soff[j] = (uint32_t)(m0 + r) * (uint32_t)K + cs * 8;
    } else {
      const int q2 = q - ACH;
      const int r = q2 >> 2, cs = (q2 & 3) ^ ((r >> 1) & 3);
      soff[j] = (uint32_t)(n0 + r) * (uint32_t)K + cs * 8;
    }
  }

  int aoff[FM], boff[FN];
  #pragma unroll
  for (int f = 0; f < FM; ++f) {
    const int r = wm * (BM / 2) + f * 16 + lrow;
    aoff[f] = r * 64 + ((lkc ^ ((r >> 1) & 3)) << 4);
  }
  #pragma unroll
  for (int n_ = 0; n_ < FN; ++n_) {
    const int r = wn * (BN / 4) + n_ * 16 + lrow;
    boff[n_] = BM * 64 + r * 64 + ((lkc ^ ((r >> 1) & 3)) << 4);
  }

  f32x4_v acc[FM][FN];
  #pragma unroll
  for (int f = 0; f < FM; ++f)
    #pragma unroll
    for (int n_ = 0; n_ < FN; ++n_) acc[f][n_] = (f32x4_v){0.f, 0.f, 0.f, 0.f};

  const int NT = K / BK;

  for (int tt = 0; tt < 3; ++tt) {
    char* sb = smem + tt * SLOT;
    #pragma unroll
    for (int j = 0; j < L; ++j)
      gload16((j < JA ? A : Bt) + soff[j] + tt * BK,
              (unsigned short*)(sb + (tid + j * 512) * 16));
  }
  if constexpr (L == 4) { VMCNT(8); } else { VMCNT(6); }
  __builtin_amdgcn_s_barrier();
  __builtin_amdgcn_sched_barrier(0);

  bf16x8 bfr[FN];
  for (int t = 0; t < NT; ++t) {
    const char* sb = smem + (t & 3) * SLOT;
    char* pb = smem + ((t + 3) & 3) * SLOT;
    const bool do_stage = (t + 3 < NT);
    #pragma unroll
    for (int p = 0; p < P; ++p) {
      bf16x8 af[4];
      #pragma unroll
      for (int m_ = 0; m_ < 4; ++m_)
        af[m_] = *(const bf16x8*)(sb + aoff[p * 4 + m_]);
      if (p == 0) {
        #pragma unroll
        for (int n_ = 0; n_ < FN; ++n_)
          bfr[n_] = *(const bf16x8*)(sb + boff[n_]);
      }
      if (do_stage) {
        #pragma unroll
        for (int jj = 0; jj < LPP; ++jj) {
          const int j = p * LPP + jj;
          gload16((j < JA ? A : Bt) + soff[j] + (t + 3) * BK,
                  (unsigned short*)(pb + (tid + j * 512) * 16));
        }
      }
      __builtin_amdgcn_s_barrier();
      __builtin_amdgcn_s_setprio(1);
      #pragma unroll
      for (int m_ = 0; m_ < 4; ++m_)
        #pragma unroll
        for (int n_ = 0; n_ < FN; ++n_)
          acc[p * 4 + m_][n_] = __builtin_amdgcn_mfma_f32_16x16x32_bf16(
              af[m_], bfr[n_], acc[p * 4 + m_][n_], 0, 0, 0);
      __builtin_amdgcn_s_setprio(0);
      if (p == P - 1) {
        if (t < NT - 3)       { if constexpr (L == 4) { VMCNT(8); } else { VMCNT(6); } }
        else if (t == NT - 3) { if constexpr (L == 4) { VMCNT(4); } else { VMCNT(3); } }
        else if (t == NT - 2) { VMCNT(0); }
      }
      __builtin_amdgcn_s_barrier();
      __builtin_amdgcn_sched_barrier(0);
    }
  }

  const int colq = l & 15;
  const int rowq = (l >> 4) * 4;
  if constexpr (EPI == 0) {
    #pragma unroll
    for (int f = 0; f < FM; ++f)
      #pragma unroll
      for (int n_ = 0; n_ < FN; ++n_) {
        const int col = n0 + wn * (BN / 4) + n_ * 16 + colq;
        #pragma unroll
        for (int r = 0; r < 4; ++r) {
          const int row = m0 + wm * (BM / 2) + f * 16 + rowq + r;
          Cbf[(size_t)row * N + col] = f2bf(gelu_fast(acc[f][n_][r]));
        }
      }
  } else {
    const int e = *eidx_p;
    const float* brow = bias + (size_t)e * N;
    #pragma unroll
    for (int n_ = 0; n_ < FN; ++n_) {
      const int col = n0 + wn * (BN / 4) + n_ * 16 + colq;
      const float bv = brow[col];
      #pragma unroll
      for (int f = 0; f < FM; ++f)
        #pragma unroll
        for (int r = 0; r < 4; ++r) {
          const int row = m0 + wm * (BM / 2) + f * 16 + rowq + r;
          Cf[(size_t)row * N + col] = acc[f][n_][r] + bv;
        }
    }
  }
}

// ---------------------------------------------------------------------------
// MEASUREMENT ROUND: mem_kernel launched 5x (idempotent — reads inputs only,
// writes identical values). mem_dur = (total_R6 - total_R5) / 4.
// GEMMs byte-identical to R5. No functional change.
// ---------------------------------------------------------------------------
extern "C" void kernel_launch(void* const* d_in, const int* in_sizes, int n_in,
                              void* d_out, int out_size, void* d_ws, size_t ws_size,
                              hipStream_t stream)
{
  const float* inputs     = (const float*)d_in[0];
  const float* basis_up   = (const float*)d_in[1];
  const float* basis_down = (const float*)d_in[2];
  const float* cup        = (const float*)d_in[3];
  const float* cdn        = (const float*)d_in[4];
  const float* bias       = (const float*)d_in[5];
  const int*   eidx       = (const int*)d_in[6];
  float*       out        = (float*)d_out;

  char* ws = (char*)d_ws;
  unsigned short* A_bf   = (unsigned short*)(ws);                  // 16 MB
  unsigned short* WupT   = (unsigned short*)(ws + (16u << 20));    //  8 MB
  unsigned short* WdnT   = (unsigned short*)(ws + (24u << 20));    //  8 MB
  unsigned short* hidden = (unsigned short*)(ws + (32u << 20));    // 64 MB

  // 5x launch: 4 extra replicas for timing isolation (idempotent)
  for (int rep = 0; rep < 5; ++rep)
    mem_kernel<<<2560, 256, 0, stream>>>(
        inputs, basis_up, basis_down, cup, cdn, eidx, A_bf, WupT, WdnT);

  gemm8p<256, 256, 8, 8, 0><<<512, 512, 0, stream>>>(
      A_bf, WupT, hidden, nullptr, nullptr, nullptr, NTOK, HDDIM, DMODEL);

  gemm8p<128, 256, 8, 4, 1><<<256, 512, 0, stream>>>(
      hidden, WdnT, nullptr, out, bias, eidx, NTOK, DMODEL, HDDIM);
}

// Round 7
// 398.648 us; speedup vs baseline: 3.4828x; 3.4828x over previous
//
#include <hip/hip_runtime.h>
#include <cstdint>

#define NTOK 8192
#define DMODEL 1024
#define HDDIM 4096
#define NVEC 32

typedef float f32x4_v __attribute__((ext_vector_type(4)));
typedef __bf16 bf16x8 __attribute__((ext_vector_type(8)));
typedef unsigned short u16x4 __attribute__((ext_vector_type(4)));
typedef unsigned short u16x8 __attribute__((ext_vector_type(8)));

__device__ __forceinline__ unsigned short f2bf(float f) {
  union { float f; uint32_t u; } x; x.f = f;
  uint32_t r = (x.u + 0x7FFFu + ((x.u >> 16) & 1u)) >> 16;
  return (unsigned short)r;
}

// tanh-form GELU via single v_exp_f32; |err| vs erf-gelu <= ~5e-4.
__device__ __forceinline__ float gelu_fast(float x) {
  float t = x * x;
  float z = x * (2.3022082f + 0.1029440f * t);
  float e = exp2f(-z);
  return x / (1.0f + e);
}

#define VMCNT(n) asm volatile("s_waitcnt vmcnt(" #n ")" ::: "memory")

__device__ __forceinline__ void gload16(const unsigned short* g, unsigned short* lds)
{
  __builtin_amdgcn_global_load_lds((__attribute__((address_space(1))) void*)g,
                                   (__attribute__((address_space(3))) void*)lds,
                                   16, 0, 0);
}

// ---------------------------------------------------------------------------
// Reconstruct + transpose, streaming layout: tile = 16 rows x 256 cols.
// Each wave reads 1 KB CONTIGUOUS per row-segment (64 lanes x 16B); v-loop
// start staggered by block to decorrelate the 32 basis streams.
// outT[y][x] (bf16, ld=X) = sum_v c[v]*basis[v][x][y]
// ---------------------------------------------------------------------------
__device__ __forceinline__
void reconstruct_body(const float* __restrict__ basis,
                      const float* __restrict__ coeffs,
                      int e, unsigned short* __restrict__ outT,
                      int X, int Y, int tile, int bid, char* smem)
{
  float (*lds)[260] = (float (*)[260])smem;   // [16][260] f32 = 16.6 KB
  const int xtiles = X >> 4;                  // 16 rows per tile
  const int bx = tile % xtiles;
  const int by = tile / xtiles;
  const int x0 = bx << 4, y0 = by << 8;       // 256 cols per tile
  const int t  = threadIdx.x;
  const int w  = t >> 6, l = t & 63;

  f32x4_v acc[4];
  #pragma unroll
  for (int i = 0; i < 4; ++i) acc[i] = (f32x4_v){0.f, 0.f, 0.f, 0.f};

  const size_t mat = (size_t)X * (size_t)Y;
  uint32_t roff[4];
  #pragma unroll
  for (int i = 0; i < 4; ++i)
    roff[i] = (uint32_t)(x0 + w * 4 + i) * (uint32_t)Y + (uint32_t)(y0 + l * 4);

  #pragma unroll 2
  for (int vv = 0; vv < NVEC; ++vv) {
    const int v = (vv + bid) & (NVEC - 1);     // stagger streams across blocks
    const float cv = coeffs[e * NVEC + v];
    const float* pv = basis + (size_t)v * mat;
    #pragma unroll
    for (int i = 0; i < 4; ++i) {
      f32x4_v d = *(const f32x4_v*)(pv + roff[i]);
      acc[i] += cv * d;
    }
  }

  // transpose via LDS: store [x_local][y_local]
  #pragma unroll
  for (int i = 0; i < 4; ++i)
    *(f32x4_v*)&lds[w * 4 + i][l * 4] = acc[i];
  __syncthreads();

  // write: thread t owns y_local = t; emits 16 bf16 (32 B) of row y
  const int y = y0 + t;
  u16x8 o0, o1;
  #pragma unroll
  for (int x = 0; x < 8; ++x)  o0[x] = f2bf(lds[x][t]);
  #pragma unroll
  for (int x = 0; x < 8; ++x)  o1[x] = f2bf(lds[8 + x][t]);
  unsigned short* dst = outT + (size_t)y * X + x0;
  *(u16x8*)dst = o0;
  *(u16x8*)(dst + 8) = o1;
}

// ---------------------------------------------------------------------------
// Merged memory kernel: rec_up (0..1023) | rec_dn (1024..2047) | cvt (2048..2559)
// ---------------------------------------------------------------------------
#define CVT_BLKS 512

__global__ __launch_bounds__(256)
void mem_kernel(const float* __restrict__ inputs,
                const float* __restrict__ basis_up,
                const float* __restrict__ basis_down,
                const float* __restrict__ cup,
                const float* __restrict__ cdn,
                const int* __restrict__ eidx_p,
                unsigned short* __restrict__ A_bf,
                unsigned short* __restrict__ WupT,
                unsigned short* __restrict__ WdnT)
{
  __shared__ __align__(16) char smem[16 * 260 * 4];
  const int bid = blockIdx.x;
  if (bid < 1024) {
    // rec_up: X=DMODEL rows(16/tile): 64 xtiles * 16 ytiles = 1024
    reconstruct_body(basis_up, cup, *eidx_p, WupT, DMODEL, HDDIM, bid, bid, smem);
  } else if (bid < 2048) {
    // rec_dn: X=HDDIM: 256 xtiles * 4 ytiles = 1024
    reconstruct_body(basis_down, cdn, *eidx_p, WdnT, HDDIM, DMODEL, bid - 1024, bid, smem);
  } else {
    const int n4 = NTOK * DMODEL / 4;
    const int stride = CVT_BLKS * 256;
    for (int i = (bid - 2048) * 256 + threadIdx.x; i < n4; i += stride) {
      f32x4_v v = ((const f32x4_v*)inputs)[i];
      u16x4 u;
      #pragma unroll
      for (int j = 0; j < 4; ++j) u[j] = f2bf(v[j]);
      ((u16x4*)A_bf)[i] = u;
    }
  }
}

// ---------------------------------------------------------------------------
// 8-wave deep-pipelined GEMM (unchanged from R5; measured g1+g2 ~= 175 us)
// ---------------------------------------------------------------------------
template<int BM, int BN, int CHM, int CHN, int EPI>
__global__ __launch_bounds__(512)
void gemm8p(const unsigned short* __restrict__ A,
            const unsigned short* __restrict__ Bt,
            unsigned short* __restrict__ Cbf,
            float* __restrict__ Cf,
            const float* __restrict__ bias,
            const int* __restrict__ eidx_p,
            int M, int N, int K)
{
  constexpr int BK   = 32;
  constexpr int FM   = BM / 32;
  constexpr int FN   = BN / 64;
  constexpr int P    = (FM * FN) / 16;
  constexpr int SLOT = (BM + BN) * BK * 2;
  constexpr int L    = SLOT / 16 / 512;
  constexpr int LPP  = L / P;
  constexpr int ACH  = BM * 4;
  constexpr int JA   = ACH / 512;

  __shared__ __align__(16) char smem[4 * SLOT];

  const int nb  = N / BN;
  const int ncn = nb / CHN;
  const int xcd = blockIdx.x & 7;
  const int idx = blockIdx.x >> 3;
  const int bm  = (xcd / ncn) * CHM + idx / CHN;
  const int bn  = (xcd % ncn) * CHN + idx % CHN;
  const int m0 = bm * BM, n0 = bn * BN;

  const int tid = threadIdx.x;
  const int w = tid >> 6, l = tid & 63;
  const int wm = w >> 2, wn = w & 3;
  const int lrow = l & 15, lkc = l >> 4;

  uint32_t soff[L];
  #pragma unroll
  for (int j = 0; j < L; ++j) {
    const int q = tid + j * 512;
    if (j < JA) {
      const int r = q >> 2, cs = (q & 3) ^ ((r >> 1) & 3);
      soff[j] = (uint32_t)(m0 + r) * (uint32_t)K + cs * 8;
    } else {
      const int q2 = q - ACH;
      const int r = q2 >> 2, cs = (q2 & 3) ^ ((r >> 1) & 3);
      soff[j] = (uint32_t)(n0 + r) * (uint32_t)K + cs * 8;
    }
  }

  int aoff[FM], boff[FN];
  #pragma unroll
  for (int f = 0; f < FM; ++f) {
    const int r = wm * (BM / 2) + f * 16 + lrow;
    aoff[f] = r * 64 + ((lkc ^ ((r >> 1) & 3)) << 4);
  }
  #pragma unroll
  for (int n_ = 0; n_ < FN; ++n_) {
    const int r = wn * (BN / 4) + n_ * 16 + lrow;
    boff[n_] = BM * 64 + r * 64 + ((lkc ^ ((r >> 1) & 3)) << 4);
  }

  f32x4_v acc[FM][FN];
  #pragma unroll
  for (int f = 0; f < FM; ++f)
    #pragma unroll
    for (int n_ = 0; n_ < FN; ++n_) acc[f][n_] = (f32x4_v){0.f, 0.f, 0.f, 0.f};

  const int NT = K / BK;

  for (int tt = 0; tt < 3; ++tt) {
    char* sb = smem + tt * SLOT;
    #pragma unroll
    for (int j = 0; j < L; ++j)
      gload16((j < JA ? A : Bt) + soff[j] + tt * BK,
              (unsigned short*)(sb + (tid + j * 512) * 16));
  }
  if constexpr (L == 4) { VMCNT(8); } else { VMCNT(6); }
  __builtin_amdgcn_s_barrier();
  __builtin_amdgcn_sched_barrier(0);

  bf16x8 bfr[FN];
  for (int t = 0; t < NT; ++t) {
    const char* sb = smem + (t & 3) * SLOT;
    char* pb = smem + ((t + 3) & 3) * SLOT;
    const bool do_stage = (t + 3 < NT);
    #pragma unroll
    for (int p = 0; p < P; ++p) {
      bf16x8 af[4];
      #pragma unroll
      for (int m_ = 0; m_ < 4; ++m_)
        af[m_] = *(const bf16x8*)(sb + aoff[p * 4 + m_]);
      if (p == 0) {
        #pragma unroll
        for (int n_ = 0; n_ < FN; ++n_)
          bfr[n_] = *(const bf16x8*)(sb + boff[n_]);
      }
      if (do_stage) {
        #pragma unroll
        for (int jj = 0; jj < LPP; ++jj) {
          const int j = p * LPP + jj;
          gload16((j < JA ? A : Bt) + soff[j] + (t + 3) * BK,
                  (unsigned short*)(pb + (tid + j * 512) * 16));
        }
      }
      __builtin_amdgcn_s_barrier();
      __builtin_amdgcn_s_setprio(1);
      #pragma unroll
      for (int m_ = 0; m_ < 4; ++m_)
        #pragma unroll
        for (int n_ = 0; n_ < FN; ++n_)
          acc[p * 4 + m_][n_] = __builtin_amdgcn_mfma_f32_16x16x32_bf16(
              af[m_], bfr[n_], acc[p * 4 + m_][n_], 0, 0, 0);
      __builtin_amdgcn_s_setprio(0);
      if (p == P - 1) {
        if (t < NT - 3)       { if constexpr (L == 4) { VMCNT(8); } else { VMCNT(6); } }
        else if (t == NT - 3) { if constexpr (L == 4) { VMCNT(4); } else { VMCNT(3); } }
        else if (t == NT - 2) { VMCNT(0); }
      }
      __builtin_amdgcn_s_barrier();
      __builtin_amdgcn_sched_barrier(0);
    }
  }

  const int colq = l & 15;
  const int rowq = (l >> 4) * 4;
  if constexpr (EPI == 0) {
    #pragma unroll
    for (int f = 0; f < FM; ++f)
      #pragma unroll
      for (int n_ = 0; n_ < FN; ++n_) {
        const int col = n0 + wn * (BN / 4) + n_ * 16 + colq;
        #pragma unroll
        for (int r = 0; r < 4; ++r) {
          const int row = m0 + wm * (BM / 2) + f * 16 + rowq + r;
          Cbf[(size_t)row * N + col] = f2bf(gelu_fast(acc[f][n_][r]));
        }
      }
  } else {
    const int e = *eidx_p;
    const float* brow = bias + (size_t)e * N;
    #pragma unroll
    for (int n_ = 0; n_ < FN; ++n_) {
      const int col = n0 + wn * (BN / 4) + n_ * 16 + colq;
      const float bv = brow[col];
      #pragma unroll
      for (int f = 0; f < FM; ++f)
        #pragma unroll
        for (int r = 0; r < 4; ++r) {
          const int row = m0 + wm * (BM / 2) + f * 16 + rowq + r;
          Cf[(size_t)row * N + col] = acc[f][n_][r] + bv;
        }
    }
  }
}

// ---------------------------------------------------------------------------
extern "C" void kernel_launch(void* const* d_in, const int* in_sizes, int n_in,
                              void* d_out, int out_size, void* d_ws, size_t ws_size,
                              hipStream_t stream)
{
  const float* inputs     = (const float*)d_in[0];
  const float* basis_up   = (const float*)d_in[1];
  const float* basis_down = (const float*)d_in[2];
  const float* cup        = (const float*)d_in[3];
  const float* cdn        = (const float*)d_in[4];
  const float* bias       = (const float*)d_in[5];
  const int*   eidx       = (const int*)d_in[6];
  float*       out        = (float*)d_out;

  char* ws = (char*)d_ws;
  unsigned short* A_bf   = (unsigned short*)(ws);                  // 16 MB
  unsigned short* WupT   = (unsigned short*)(ws + (16u << 20));    //  8 MB
  unsigned short* WdnT   = (unsigned short*)(ws + (24u << 20));    //  8 MB
  unsigned short* hidden = (unsigned short*)(ws + (32u << 20));    // 64 MB

  mem_kernel<<<2560, 256, 0, stream>>>(
      inputs, basis_up, basis_down, cup, cdn, eidx, A_bf, WupT, WdnT);

  gemm8p<256, 256, 8, 8, 0><<<512, 512, 0, stream>>>(
      A_bf, WupT, hidden, nullptr, nullptr, nullptr, NTOK, HDDIM, DMODEL);

  gemm8p<128, 256, 8, 4, 1><<<256, 512, 0, stream>>>(
      hidden, WdnT, nullptr, out, bias, eidx, NTOK, DMODEL, HDDIM);
}